// Round 9
// baseline (23475.410 us; speedup 1.0000x reference)
//
#include <hip/hip_runtime.h>
#include <math.h>

#pragma clang fp contract(off)

#define NS 1024
#define NU 8192
#define FINF __builtin_huge_valf()

// ws layout (int units): [0] byteMode flag; [64..8255] order;
// [8256..41023] wl (floats, sorted workloads); [41024..303167] packed masks
#define WS_ORDER 64
#define WS_WL 8256
#define WS_PM 41024
#define WS_NEED_BYTES ((size_t)(WS_PM + NU * 32) * 4 + 256)

// ---------------------------------------------------------------------------
// Wave64 reductions via DPP scan (row_shr 1/2/4/8 + row_bcast 15/31); total
// lands in lane 63, broadcast via v_readlane. HW-verified R5-R8 (absmax 0).
// ---------------------------------------------------------------------------
template <int CTRL, unsigned IDBITS>
__device__ __forceinline__ float dpp_take(float v) {
    return __int_as_float(__builtin_amdgcn_update_dpp(
        (int)IDBITS, __float_as_int(v), CTRL, 0xF, 0xF, false));
}
__device__ __forceinline__ float bcast63(float v) {
    return __int_as_float(__builtin_amdgcn_readlane(__float_as_int(v), 63));
}
__device__ __forceinline__ float wsum(float x) {
    x += dpp_take<0x111, 0u>(x);
    x += dpp_take<0x112, 0u>(x);
    x += dpp_take<0x114, 0u>(x);
    x += dpp_take<0x118, 0u>(x);
    x += dpp_take<0x142, 0u>(x);
    x += dpp_take<0x143, 0u>(x);
    return bcast63(x);
}
__device__ __forceinline__ float wmax(float x) {
    x = fmaxf(x, dpp_take<0x111, 0xFF800000u>(x));
    x = fmaxf(x, dpp_take<0x112, 0xFF800000u>(x));
    x = fmaxf(x, dpp_take<0x114, 0xFF800000u>(x));
    x = fmaxf(x, dpp_take<0x118, 0xFF800000u>(x));
    x = fmaxf(x, dpp_take<0x142, 0xFF800000u>(x));
    x = fmaxf(x, dpp_take<0x143, 0xFF800000u>(x));
    return bcast63(x);
}
__device__ __forceinline__ float wmin(float x) {
    x = fminf(x, dpp_take<0x111, 0x7F800000u>(x));
    x = fminf(x, dpp_take<0x112, 0x7F800000u>(x));
    x = fminf(x, dpp_take<0x114, 0x7F800000u>(x));
    x = fminf(x, dpp_take<0x118, 0x7F800000u>(x));
    x = fminf(x, dpp_take<0x142, 0x7F800000u>(x));
    x = fminf(x, dpp_take<0x143, 0x7F800000u>(x));
    return bcast63(x);
}

// Correctly-rounded f32 division via Markstein fma sequence (bit == IEEE '/').
__device__ __forceinline__ float div_rn(float x, float d, float r) {
    float q = x * r;
    float e = __builtin_fmaf(-d, q, x);
    return __builtin_fmaf(e, r, q);
}

// ---------------------------------------------------------------------------
// Kernel 0: detect mask encoding.
// ---------------------------------------------------------------------------
__global__ void detect_kernel(const unsigned* __restrict__ m, int* __restrict__ flag) {
    __shared__ int s_any;
    if (threadIdx.x == 0) s_any = 0;
    __syncthreads();
    int bad = 0;
    for (int i = threadIdx.x; i < 65536; i += 256) {
        unsigned v = m[i];
        bad |= !(v == 0u || v == 1u || v == 0x3F800000u);
    }
    if (bad) s_any = 1;
    __syncthreads();
    if (threadIdx.x == 0) flag[0] = s_any;
}

// ---------------------------------------------------------------------------
// Kernel 1: stable rank sort of users[:,2] -> order[rank] = i
// ---------------------------------------------------------------------------
__global__ void rank_kernel(const float* __restrict__ users, int* __restrict__ order) {
    __shared__ float keys[2048];
    const int i = blockIdx.x * 256 + threadIdx.x;
    const float key = users[i * 6 + 2];
    int rank = 0;
    for (int base = 0; base < NU; base += 2048) {
        __syncthreads();
        for (int k = threadIdx.x; k < 2048; k += 256)
            keys[k] = users[(base + k) * 6 + 2];
        __syncthreads();
        for (int k = 0; k < 2048; ++k) {
            float kj = keys[k];
            int j = base + k;
            rank += (kj < key) || ((kj == key) && (j < i));
        }
    }
    order[rank] = i;
}

// ---------------------------------------------------------------------------
// Kernel 1b: gather workloads in sorted order
// ---------------------------------------------------------------------------
__global__ void gather_kernel(const float* __restrict__ users, const int* __restrict__ order,
                              float* __restrict__ wl) {
    const int stp = blockIdx.x * 256 + threadIdx.x;
    const int u = order[stp];
    float2 a = *(const float2*)(users + u * 6 + 2);
    float2 b = *(const float2*)(users + u * 6 + 4);
    *(float4*)(wl + stp * 4) = make_float4(a.x, a.y, b.x, b.y);
}

// ---------------------------------------------------------------------------
// Kernel 1c: pack masks to 1 bit/server, in sorted user order.
// ---------------------------------------------------------------------------
__global__ void pack_kernel(const void* __restrict__ masksv, const int* __restrict__ wsi,
                            const int* __restrict__ order, unsigned* __restrict__ pm) {
    const int idx = blockIdx.x * 256 + threadIdx.x;
    const int stp = idx >> 5, w = idx & 31;
    const int u = order[stp];
    const int byteMode = wsi[0];
    unsigned word = 0;
    if (byteMode) {
        const uint4* q = (const uint4*)((const unsigned char*)masksv + (size_t)u * NS + w * 32);
        uint4 a = q[0], b = q[1];
        unsigned vv[8] = {a.x, a.y, a.z, a.w, b.x, b.y, b.z, b.w};
        #pragma unroll
        for (int d = 0; d < 8; ++d) {
            #pragma unroll
            for (int i = 0; i < 4; ++i)
                if ((vv[d] >> (8 * i)) & 0xFFu) word |= 1u << (d * 4 + i);
        }
    } else {
        const int4* q = (const int4*)((const int*)masksv + (size_t)u * NS + w * 32);
        #pragma unroll
        for (int d = 0; d < 8; ++d) {
            int4 v = q[d];
            if (v.x) word |= 1u << (d * 4 + 0);
            if (v.y) word |= 1u << (d * 4 + 1);
            if (v.z) word |= 1u << (d * 4 + 2);
            if (v.w) word |= 1u << (d * 4 + 3);
        }
    }
    pm[idx] = word;
}

// ---------------------------------------------------------------------------
// Kernel 2: sequential allocator. 256 threads (4 waves), 4 servers/lane.
// 2 barriers/step; DPP intra-wave reduce + b128-vectorized LDS cross-wave
// combine; cnt via SALU ballots; fused 3-hypothesis score phase; Markstein
// exact divisions. 512 redundant blocks (block 0 writes) hold clocks.
// ---------------------------------------------------------------------------
template <bool PACKED>
__global__ __launch_bounds__(256, 1)
void alloc_kernel(const float* __restrict__ servers,
                  const float* __restrict__ users,
                  const void*  __restrict__ masksv,
                  const int*   __restrict__ wsi,
                  float* __restrict__ out) {
    const int tid  = threadIdx.x;
    const int lane = tid & 63;
    const int wid  = tid >> 6;
    const int sbase = tid * 4;
    const int byteMode = wsi[0];
    const int* __restrict__ order_g = wsi + WS_ORDER;
    const float* __restrict__ wlf = (const float*)(wsi + WS_WL);
    const unsigned* __restrict__ pm = (const unsigned*)(wsi + WS_PM);
    const unsigned char* __restrict__ mbytes = (const unsigned char*)masksv;
    const int*           __restrict__ mwords = (const int*)masksv;

    __shared__ float  s_res[NU];
    __shared__ float4 rA4[4][2];   // [w][0]={sumF,cnt,mxB,mnB} [w][1]={h10,h0,-,-}
    __shared__ float4 rM4[4][2];   // [w][0]={s2,sm0,sm1,sm2}   [w][1]={id0,id1,id2,-}

    // per-thread state: servers sbase..sbase+3 (registers)
    float c[4][4], rc[4][4], t[4][4], f[4][4], B[4], us[4], fs[4];
    int virg = 0xF;

    #pragma unroll
    for (int j = 0; j < 4; ++j) {
        #pragma unroll
        for (int k = 0; k < 4; ++k) {
            float cv = servers[(sbase + j) * 7 + 3 + k];
            c[j][k] = cv;
            rc[j][k] = 1.0f / cv;        // RN reciprocal for Markstein
            t[j][k] = cv;
            f[j][k] = 0.0f;
        }
        B[j] = 0.0f; us[j] = 0.0f; fs[j] = 0.0f;
    }

    auto stepf = [&](int stp, unsigned vm4, float4 wl) {
        const float w0 = __int_as_float(__builtin_amdgcn_readfirstlane(__float_as_int(wl.x)));
        const float w1 = __int_as_float(__builtin_amdgcn_readfirstlane(__float_as_int(wl.y)));
        const float w2 = __int_as_float(__builtin_amdgcn_readfirstlane(__float_as_int(wl.z)));
        const float w3 = __int_as_float(__builtin_amdgcn_readfirstlane(__float_as_int(wl.w)));

        // ---- phase A
        int vbits = 0;
        float sumF = 0.0f, mxB = -FINF, mnB = FINF;
        #pragma unroll
        for (int j = 0; j < 4; ++j) {
            bool ok = ((vm4 >> j) & 1u) &&
                      (t[j][0] >= w0) && (t[j][1] >= w1) &&
                      (t[j][2] >= w2) && (t[j][3] >= w3);
            if (ok) {
                vbits |= 1 << j;
                sumF += fs[j];
                mxB = fmaxf(mxB, B[j]);
                mnB = fminf(mnB, B[j]);
            }
        }
        // per-wave valid count via ballots (SALU) — exact integer in f32
        int cw = __popcll(__ballot(vbits & 1)) + __popcll(__ballot(vbits & 2))
               + __popcll(__ballot(vbits & 4)) + __popcll(__ballot(vbits & 8));
        sumF = wsum(sumF);
        mxB  = wmax(mxB);
        mnB  = wmin(mnB);
        unsigned long long bV  = __ballot((vbits & virg) != 0);
        unsigned long long bNV = __ballot((vbits & ~virg & 0xF) != 0);
        if (lane == 0) {
            rA4[wid][0] = make_float4(sumF, (float)cw, mxB, mnB);
            rA4[wid][1] = make_float4(bV ? 1.0f : 0.0f, bNV ? 1.0f : 0.0f, 0.0f, 0.0f);
        }
        __syncthreads();   // B1
        float4 a0 = rA4[0][0], a1 = rA4[1][0], a2 = rA4[2][0], a3 = rA4[3][0];
        float4 g0 = rA4[0][1], g1 = rA4[1][1], g2 = rA4[2][1], g3 = rA4[3][1];
        float cnt = ((a0.y + a1.y) + a2.y) + a3.y;
        sumF = ((a0.x + a1.x) + a2.x) + a3.x;
        mxB  = fmaxf(fmaxf(a0.z, a1.z), fmaxf(a2.z, a3.z));
        mnB  = fminf(fminf(a0.w, a1.w), fminf(a2.w, a3.w));
        bool hasC10 = (g0.x + g1.x + g2.x + g3.x) > 0.0f;
        bool hasC0  = (g0.y + g1.y + g2.y + g3.y) > 0.0f;

        if (cnt > 0.0f) {
            float n = cnt * 4.0f;
            float mean = sumF / fmaxf(n, 1.0f);
            int row = (mean <= 0.2f) ? 0 : ((mean <= 0.5f) ? 1 : 2);
            float tw_[3];
            if (row == 0)      { tw_[0] = 0.9f; tw_[1] = 0.8f; tw_[2] = 0.6f; }
            else if (row == 1) { tw_[0] = 0.6f; tw_[1] = 0.5f; tw_[2] = 0.4f; }
            else               { tw_[0] = 0.4f; tw_[1] = 0.2f; tw_[2] = 0.1f; }
            // C-normalization folds exactly: c-term = (virgin && both) ? bb : 0
            const bool both = hasC10 && hasC0;
            float aH[3], cH[3];
            #pragma unroll
            for (int h = 0; h < 3; ++h) {
                aH[h] = tw_[h] + 0.3f;
                float bb = (1.0f - tw_[h]) + 0.55f;
                cH[h] = both ? bb : 0.0f;
            }
            float dB = mxB - mnB;
            float rdB = (dB != 0.0f) ? (1.0f / dB) : 0.0f;   // one IEEE div, uniform

            // ---- fused: var partials + bi + 3-hypothesis (smin, first-idx)
            float s2 = 0.0f;
            float bi[4];
            #pragma unroll
            for (int j = 0; j < 4; ++j) {
                if ((vbits >> j) & 1) {
                    float d0 = f[j][0] - mean;
                    float d1 = f[j][1] - mean;
                    float d2 = f[j][2] - mean;
                    float d3 = f[j][3] - mean;
                    s2 += d0 * d0 + d1 * d1 + d2 * d2 + d3 * d3;
                }
                bi[j] = (dB != 0.0f) ? div_rn(B[j] - mnB, dB, rdB) : 0.0f;
            }
            s2 = wsum(s2);

            float smH[3]; int idH[3];
            #pragma unroll
            for (int h = 0; h < 3; ++h) {
                float sc[4];
                float lm = FINF;
                #pragma unroll
                for (int j = 0; j < 4; ++j) {
                    sc[j] = aH[h] * bi[j] + (((virg >> j) & 1) ? cH[h] : 0.0f);
                    if ((vbits >> j) & 1) lm = fminf(lm, sc[j]);
                }
                float sm = wmin(lm);
                int li = 1024;
                #pragma unroll
                for (int j = 3; j >= 0; --j)       // descending: last write = smallest j
                    if (((vbits >> j) & 1) && sc[j] == sm) li = sbase + j;
                unsigned long long bm = __ballot(li != 1024);
                int src = __ffsll(bm) - 1;
                int gi = 1024;
                if (bm) gi = __builtin_amdgcn_readlane(li, src);
                smH[h] = sm; idH[h] = gi;
            }
            if (lane == 0) {
                rM4[wid][0] = make_float4(s2, smH[0], smH[1], smH[2]);
                rM4[wid][1] = make_float4(__int_as_float(idH[0]), __int_as_float(idH[1]),
                                          __int_as_float(idH[2]), 0.0f);
            }
            __syncthreads();   // B2
            float4 m0 = rM4[0][0], m1 = rM4[1][0], m2 = rM4[2][0], m3 = rM4[3][0];
            float4 i0 = rM4[0][1], i1 = rM4[1][1], i2 = rM4[2][1], i3 = rM4[3][1];
            s2 = ((m0.x + m1.x) + m2.x) + m3.x;
            float var = s2 / fmaxf(n - 1.0f, 1.0f);
            float sd  = sqrtf(var);
            int col = (sd <= 0.1f) ? 0 : ((sd <= 0.3f) ? 1 : 2);
            // select col hypothesis from registers (col uniform)
            auto pickv = [&](float4 m) { return (col == 0) ? m.y : ((col == 1) ? m.z : m.w); };
            auto picki = [&](float4 i) {
                return __float_as_int((col == 0) ? i.x : ((col == 1) ? i.y : i.z));
            };
            float bv2 = pickv(m0); int bI = picki(i0);
            {
                float ov = pickv(m1); int oi = picki(i1);
                if (ov < bv2 || (ov == bv2 && oi < bI)) { bv2 = ov; bI = oi; }
                ov = pickv(m2); oi = picki(i2);
                if (ov < bv2 || (ov == bv2 && oi < bI)) { bv2 = ov; bI = oi; }
                ov = pickv(m3); oi = picki(i3);
                if (ov < bv2 || (ov == bv2 && oi < bI)) { bv2 = ov; bI = oi; }
            }
            const int chosen = bI;
            if (tid == 0) s_res[stp] = (float)chosen;

            // ---- update chosen server (owning thread; static dispatch)
            if ((chosen >> 2) == tid) {
                const int wj = chosen & 3;
                #pragma unroll
                for (int j = 0; j < 4; ++j) {
                    if (wj == j) {
                        t[j][0] = t[j][0] - w0;
                        t[j][1] = t[j][1] - w1;
                        t[j][2] = t[j][2] - w2;
                        t[j][3] = t[j][3] - w3;
                        us[j] = us[j] + 1.0f;
                        virg &= ~(1 << j);
                        #pragma unroll
                        for (int k = 0; k < 4; ++k) {
                            const float mid  = (k == 0) ? 0.4f : ((k == 1) ? 0.5f : ((k == 2) ? 0.3f : 0.5f));
                            const float high = (k == 0) ? 0.8f : ((k == 1) ? 0.8f : ((k == 2) ? 0.7f : 0.8f));
                            const float hm   = high - mid;
                            const float rmid = 1.0f / mid;
                            const float rhm  = 1.0f / hm;
                            float rem = c[j][k] - t[j][k];
                            float x = div_rn(rem, c[j][k], rc[j][k]);
                            float fv;
                            if (x <= 0.0f)      fv = 0.0f;
                            else if (x <= mid)  fv = div_rn(x, mid, rmid);
                            else if (x <= high) fv = div_rn(high - x, hm, rhm);
                            else                fv = 0.0f;
                            f[j][k] = fv;
                        }
                        fs[j] = ((f[j][0] + f[j][1]) + f[j][2]) + f[j][3];
                        float sB = ((div_rn(t[j][0], c[j][0], rc[j][0])
                                   + div_rn(t[j][1], c[j][1], rc[j][1]))
                                   + div_rn(t[j][2], c[j][2], rc[j][2]))
                                   + div_rn(t[j][3], c[j][3], rc[j][3]);
                        B[j] = 1.0f - sB * 0.25f;
                    }
                }
            }
        } else {
            if (tid == 0) s_res[stp] = -1.0f;
            __syncthreads();   // close the step: protect rA4 WAR (uniform branch)
        }
    };

    if (PACKED) {
        unsigned mcur = pm[0 * 32 + (tid >> 3)];
        float4   wcur = *(const float4*)(wlf + 0 * 4);
        const int sh = (tid & 7) * 4;
        #pragma unroll 1
        for (int stp = 0; stp < NU; ++stp) {
            const int nxt = (stp + 1 < NU) ? (stp + 1) : (NU - 1);
            unsigned mnx = pm[nxt * 32 + (tid >> 3)];
            float4   wnx = *(const float4*)(wlf + nxt * 4);
            stepf(stp, (mcur >> sh) & 0xFu, wcur);
            mcur = mnx; wcur = wnx;
        }
    } else {
        #pragma unroll 1
        for (int stp = 0; stp < NU; ++stp) {
            int u = order_g[stp];
            unsigned vm = 0;
            if (byteMode) {
                uchar4 mv = *(const uchar4*)(mbytes + (size_t)u * NS + sbase);
                vm = (mv.x ? 1u : 0u) | (mv.y ? 2u : 0u) | (mv.z ? 4u : 0u) | (mv.w ? 8u : 0u);
            } else {
                int4 mv = *(const int4*)(mwords + (size_t)u * NS + sbase);
                vm = (mv.x ? 1u : 0u) | (mv.y ? 2u : 0u) | (mv.z ? 4u : 0u) | (mv.w ? 8u : 0u);
            }
            float2 a2 = *(const float2*)(users + u * 6 + 2);
            float2 b2 = *(const float2*)(users + u * 6 + 4);
            stepf(stp, vm, make_float4(a2.x, a2.y, b2.x, b2.y));
        }
    }

    // ---- epilogue (block 0 only)
    __syncthreads();
    if (blockIdx.x != 0) return;
    float ac = 0.0f;
    for (int i = tid; i < NU; i += 256) {
        float v = s_res[i];
        out[order_g[i]] = v;
        ac += (v != -1.0f) ? 1.0f : 0.0f;
    }
    float uc = 0.0f;
    #pragma unroll
    for (int j = 0; j < 4; ++j) {
        out[NU + sbase + j] = us[j];
        uc += (us[j] != 0.0f) ? 1.0f : 0.0f;
    }
    ac = wsum(ac);
    uc = wsum(uc);
    if (lane == 0) rA4[wid][0] = make_float4(ac, uc, 0.0f, 0.0f);
    __syncthreads();
    if (tid == 0) {
        float at = ((rA4[0][0].x + rA4[1][0].x) + rA4[2][0].x) + rA4[3][0].x;
        float ut = ((rA4[0][0].y + rA4[1][0].y) + rA4[2][0].y) + rA4[3][0].y;
        out[NU + NS]     = at / 8192.0f;
        out[NU + NS + 1] = ut / 1024.0f;
    }
}

// ---------------------------------------------------------------------------
extern "C" void kernel_launch(void* const* d_in, const int* in_sizes, int n_in,
                              void* d_out, int out_size, void* d_ws, size_t ws_size,
                              hipStream_t stream) {
    const float* servers = (const float*)d_in[0];
    const float* users   = (const float*)d_in[1];
    const void*  masks   = d_in[2];
    int*   wsi = (int*)d_ws;
    float* out = (float*)d_out;

    detect_kernel<<<1, 256, 0, stream>>>((const unsigned*)masks, wsi);
    rank_kernel<<<32, 256, 0, stream>>>(users, wsi + WS_ORDER);
    if (ws_size >= WS_NEED_BYTES) {
        gather_kernel<<<NU / 256, 256, 0, stream>>>(users, wsi + WS_ORDER, (float*)(wsi + WS_WL));
        pack_kernel<<<NU * 32 / 256, 256, 0, stream>>>(masks, wsi, wsi + WS_ORDER,
                                                       (unsigned*)(wsi + WS_PM));
        alloc_kernel<true><<<512, 256, 0, stream>>>(servers, users, masks, wsi, out);
    } else {
        alloc_kernel<false><<<512, 256, 0, stream>>>(servers, users, masks, wsi, out);
    }
}

// Round 11
// 20426.445 us; speedup vs baseline: 1.1493x; 1.1493x over previous
//
#include <hip/hip_runtime.h>
#include <math.h>

#pragma clang fp contract(off)

#define NS 1024
#define NU 8192
#define FINF __builtin_huge_valf()

// ws layout (int units): [0] byteMode flag; [64..8255] order;
// [8256..41023] wl (floats, sorted workloads); [41024..303167] packed masks
#define WS_ORDER 64
#define WS_WL 8256
#define WS_PM 41024
#define WS_NEED_BYTES ((size_t)(WS_PM + NU * 32) * 4 + 256)

// ---------------------------------------------------------------------------
// Wave64 reductions via DPP scan (row_shr 1/2/4/8 + row_bcast 15/31); total
// lands in lane 63, broadcast via v_readlane. HW-verified R5-R9 (absmax 0).
// ---------------------------------------------------------------------------
template <int CTRL, unsigned IDBITS>
__device__ __forceinline__ float dpp_take(float v) {
    return __int_as_float(__builtin_amdgcn_update_dpp(
        (int)IDBITS, __float_as_int(v), CTRL, 0xF, 0xF, false));
}
__device__ __forceinline__ float bcast63(float v) {
    return __int_as_float(__builtin_amdgcn_readlane(__float_as_int(v), 63));
}
__device__ __forceinline__ float wsum(float x) {
    x += dpp_take<0x111, 0u>(x);
    x += dpp_take<0x112, 0u>(x);
    x += dpp_take<0x114, 0u>(x);
    x += dpp_take<0x118, 0u>(x);
    x += dpp_take<0x142, 0u>(x);
    x += dpp_take<0x143, 0u>(x);
    return bcast63(x);
}
__device__ __forceinline__ float wmax(float x) {
    x = fmaxf(x, dpp_take<0x111, 0xFF800000u>(x));
    x = fmaxf(x, dpp_take<0x112, 0xFF800000u>(x));
    x = fmaxf(x, dpp_take<0x114, 0xFF800000u>(x));
    x = fmaxf(x, dpp_take<0x118, 0xFF800000u>(x));
    x = fmaxf(x, dpp_take<0x142, 0xFF800000u>(x));
    x = fmaxf(x, dpp_take<0x143, 0xFF800000u>(x));
    return bcast63(x);
}
__device__ __forceinline__ float wmin(float x) {
    x = fminf(x, dpp_take<0x111, 0x7F800000u>(x));
    x = fminf(x, dpp_take<0x112, 0x7F800000u>(x));
    x = fminf(x, dpp_take<0x114, 0x7F800000u>(x));
    x = fminf(x, dpp_take<0x118, 0x7F800000u>(x));
    x = fminf(x, dpp_take<0x142, 0x7F800000u>(x));
    x = fminf(x, dpp_take<0x143, 0x7F800000u>(x));
    return bcast63(x);
}

// Correctly-rounded f32 division via Markstein fma sequence (bit == IEEE '/').
__device__ __forceinline__ float div_rn(float x, float d, float r) {
    float q = x * r;
    float e = __builtin_fmaf(-d, q, x);
    return __builtin_fmaf(e, r, q);
}

// ---------------------------------------------------------------------------
// Kernel 0: detect mask encoding.
// ---------------------------------------------------------------------------
__global__ void detect_kernel(const unsigned* __restrict__ m, int* __restrict__ flag) {
    __shared__ int s_any;
    if (threadIdx.x == 0) s_any = 0;
    __syncthreads();
    int bad = 0;
    for (int i = threadIdx.x; i < 65536; i += 256) {
        unsigned v = m[i];
        bad |= !(v == 0u || v == 1u || v == 0x3F800000u);
    }
    if (bad) s_any = 1;
    __syncthreads();
    if (threadIdx.x == 0) flag[0] = s_any;
}

// ---------------------------------------------------------------------------
// Kernel 1: stable rank sort of users[:,2] -> order[rank] = i
// ---------------------------------------------------------------------------
__global__ void rank_kernel(const float* __restrict__ users, int* __restrict__ order) {
    __shared__ float keys[2048];
    const int i = blockIdx.x * 256 + threadIdx.x;
    const float key = users[i * 6 + 2];
    int rank = 0;
    for (int base = 0; base < NU; base += 2048) {
        __syncthreads();
        for (int k = threadIdx.x; k < 2048; k += 256)
            keys[k] = users[(base + k) * 6 + 2];
        __syncthreads();
        for (int k = 0; k < 2048; ++k) {
            float kj = keys[k];
            int j = base + k;
            rank += (kj < key) || ((kj == key) && (j < i));
        }
    }
    order[rank] = i;
}

// ---------------------------------------------------------------------------
// Kernel 1b: gather workloads in sorted order
// ---------------------------------------------------------------------------
__global__ void gather_kernel(const float* __restrict__ users, const int* __restrict__ order,
                              float* __restrict__ wl) {
    const int stp = blockIdx.x * 256 + threadIdx.x;
    const int u = order[stp];
    float2 a = *(const float2*)(users + u * 6 + 2);
    float2 b = *(const float2*)(users + u * 6 + 4);
    *(float4*)(wl + stp * 4) = make_float4(a.x, a.y, b.x, b.y);
}

// ---------------------------------------------------------------------------
// Kernel 1c: pack masks to 1 bit/server, in sorted user order.
// ---------------------------------------------------------------------------
__global__ void pack_kernel(const void* __restrict__ masksv, const int* __restrict__ wsi,
                            const int* __restrict__ order, unsigned* __restrict__ pm) {
    const int idx = blockIdx.x * 256 + threadIdx.x;
    const int stp = idx >> 5, w = idx & 31;
    const int u = order[stp];
    const int byteMode = wsi[0];
    unsigned word = 0;
    if (byteMode) {
        const uint4* q = (const uint4*)((const unsigned char*)masksv + (size_t)u * NS + w * 32);
        uint4 a = q[0], b = q[1];
        unsigned vv[8] = {a.x, a.y, a.z, a.w, b.x, b.y, b.z, b.w};
        #pragma unroll
        for (int d = 0; d < 8; ++d) {
            #pragma unroll
            for (int i = 0; i < 4; ++i)
                if ((vv[d] >> (8 * i)) & 0xFFu) word |= 1u << (d * 4 + i);
        }
    } else {
        const int4* q = (const int4*)((const int*)masksv + (size_t)u * NS + w * 32);
        #pragma unroll
        for (int d = 0; d < 8; ++d) {
            int4 v = q[d];
            if (v.x) word |= 1u << (d * 4 + 0);
            if (v.y) word |= 1u << (d * 4 + 1);
            if (v.z) word |= 1u << (d * 4 + 2);
            if (v.w) word |= 1u << (d * 4 + 3);
        }
    }
    pm[idx] = word;
}

// ---------------------------------------------------------------------------
// Kernel 2: sequential allocator. 256 threads (4 waves), 4 servers/lane.
// 2 barriers/step; DPP intra-wave reduce + b128-vectorized LDS cross-wave
// combine; cnt via SALU ballots; fused 3-hypothesis score phase; Markstein
// exact divisions. 256 redundant blocks (1/CU — R9 showed 2/CU regresses via
// SIMD sharing); block 0 writes outputs.
// ---------------------------------------------------------------------------
template <bool PACKED>
__global__ __launch_bounds__(256, 1)
void alloc_kernel(const float* __restrict__ servers,
                  const float* __restrict__ users,
                  const void*  __restrict__ masksv,
                  const int*   __restrict__ wsi,
                  float* __restrict__ out) {
    const int tid  = threadIdx.x;
    const int lane = tid & 63;
    const int wid  = tid >> 6;
    const int sbase = tid * 4;
    const int byteMode = wsi[0];
    const int* __restrict__ order_g = wsi + WS_ORDER;
    const float* __restrict__ wlf = (const float*)(wsi + WS_WL);
    const unsigned* __restrict__ pm = (const unsigned*)(wsi + WS_PM);
    const unsigned char* __restrict__ mbytes = (const unsigned char*)masksv;
    const int*           __restrict__ mwords = (const int*)masksv;

    __shared__ float  s_res[NU];
    __shared__ float4 rA4[4][2];   // [w][0]={sumF,cnt,mxB,mnB} [w][1]={h10,h0,-,-}
    __shared__ float4 rM4[4][2];   // [w][0]={s2,sm0,sm1,sm2}   [w][1]={id0,id1,id2,-}

    // per-thread state: servers sbase..sbase+3 (registers)
    float c[4][4], rc[4][4], t[4][4], f[4][4], B[4], us[4], fs[4];
    int virg = 0xF;

    #pragma unroll
    for (int j = 0; j < 4; ++j) {
        #pragma unroll
        for (int k = 0; k < 4; ++k) {
            float cv = servers[(sbase + j) * 7 + 3 + k];
            c[j][k] = cv;
            rc[j][k] = 1.0f / cv;        // RN reciprocal for Markstein
            t[j][k] = cv;
            f[j][k] = 0.0f;
        }
        B[j] = 0.0f; us[j] = 0.0f; fs[j] = 0.0f;
    }

    auto stepf = [&](int stp, unsigned vm4, float4 wl) {
        const float w0 = __int_as_float(__builtin_amdgcn_readfirstlane(__float_as_int(wl.x)));
        const float w1 = __int_as_float(__builtin_amdgcn_readfirstlane(__float_as_int(wl.y)));
        const float w2 = __int_as_float(__builtin_amdgcn_readfirstlane(__float_as_int(wl.z)));
        const float w3 = __int_as_float(__builtin_amdgcn_readfirstlane(__float_as_int(wl.w)));

        // ---- phase A
        int vbits = 0;
        float sumF = 0.0f, mxB = -FINF, mnB = FINF;
        #pragma unroll
        for (int j = 0; j < 4; ++j) {
            bool ok = ((vm4 >> j) & 1u) &&
                      (t[j][0] >= w0) && (t[j][1] >= w1) &&
                      (t[j][2] >= w2) && (t[j][3] >= w3);
            if (ok) {
                vbits |= 1 << j;
                sumF += fs[j];
                mxB = fmaxf(mxB, B[j]);
                mnB = fminf(mnB, B[j]);
            }
        }
        // per-wave valid count via ballots (SALU) — exact integer in f32
        int cw = __popcll(__ballot(vbits & 1)) + __popcll(__ballot(vbits & 2))
               + __popcll(__ballot(vbits & 4)) + __popcll(__ballot(vbits & 8));
        sumF = wsum(sumF);
        mxB  = wmax(mxB);
        mnB  = wmin(mnB);
        unsigned long long bV  = __ballot((vbits & virg) != 0);
        unsigned long long bNV = __ballot((vbits & ~virg & 0xF) != 0);
        if (lane == 0) {
            rA4[wid][0] = make_float4(sumF, (float)cw, mxB, mnB);
            rA4[wid][1] = make_float4(bV ? 1.0f : 0.0f, bNV ? 1.0f : 0.0f, 0.0f, 0.0f);
        }
        __syncthreads();   // B1
        float4 a0 = rA4[0][0], a1 = rA4[1][0], a2 = rA4[2][0], a3 = rA4[3][0];
        float4 g0 = rA4[0][1], g1 = rA4[1][1], g2 = rA4[2][1], g3 = rA4[3][1];
        float cnt = ((a0.y + a1.y) + a2.y) + a3.y;
        sumF = ((a0.x + a1.x) + a2.x) + a3.x;
        mxB  = fmaxf(fmaxf(a0.z, a1.z), fmaxf(a2.z, a3.z));
        mnB  = fminf(fminf(a0.w, a1.w), fminf(a2.w, a3.w));
        bool hasC10 = (g0.x + g1.x + g2.x + g3.x) > 0.0f;
        bool hasC0  = (g0.y + g1.y + g2.y + g3.y) > 0.0f;

        if (cnt > 0.0f) {
            float n = cnt * 4.0f;
            float mean = sumF / fmaxf(n, 1.0f);
            int row = (mean <= 0.2f) ? 0 : ((mean <= 0.5f) ? 1 : 2);
            float tw_[3];
            if (row == 0)      { tw_[0] = 0.9f; tw_[1] = 0.8f; tw_[2] = 0.6f; }
            else if (row == 1) { tw_[0] = 0.6f; tw_[1] = 0.5f; tw_[2] = 0.4f; }
            else               { tw_[0] = 0.4f; tw_[1] = 0.2f; tw_[2] = 0.1f; }
            // C-normalization folds exactly: c-term = (virgin && both) ? bb : 0
            const bool both = hasC10 && hasC0;
            float aH[3], cH[3];
            #pragma unroll
            for (int h = 0; h < 3; ++h) {
                aH[h] = tw_[h] + 0.3f;
                float bb = (1.0f - tw_[h]) + 0.55f;
                cH[h] = both ? bb : 0.0f;
            }
            float dB = mxB - mnB;
            float rdB = (dB != 0.0f) ? (1.0f / dB) : 0.0f;   // one IEEE div, uniform

            // ---- fused: var partials + bi + 3-hypothesis (smin, first-idx)
            float s2 = 0.0f;
            float bi[4];
            #pragma unroll
            for (int j = 0; j < 4; ++j) {
                if ((vbits >> j) & 1) {
                    float d0 = f[j][0] - mean;
                    float d1 = f[j][1] - mean;
                    float d2 = f[j][2] - mean;
                    float d3 = f[j][3] - mean;
                    s2 += d0 * d0 + d1 * d1 + d2 * d2 + d3 * d3;
                }
                bi[j] = (dB != 0.0f) ? div_rn(B[j] - mnB, dB, rdB) : 0.0f;
            }
            s2 = wsum(s2);

            float smH[3]; int idH[3];
            #pragma unroll
            for (int h = 0; h < 3; ++h) {
                float sc[4];
                float lm = FINF;
                #pragma unroll
                for (int j = 0; j < 4; ++j) {
                    sc[j] = aH[h] * bi[j] + (((virg >> j) & 1) ? cH[h] : 0.0f);
                    if ((vbits >> j) & 1) lm = fminf(lm, sc[j]);
                }
                float sm = wmin(lm);
                int li = 1024;
                #pragma unroll
                for (int j = 3; j >= 0; --j)       // descending: last write = smallest j
                    if (((vbits >> j) & 1) && sc[j] == sm) li = sbase + j;
                unsigned long long bm = __ballot(li != 1024);
                int src = __ffsll(bm) - 1;
                int gi = 1024;
                if (bm) gi = __builtin_amdgcn_readlane(li, src);
                smH[h] = sm; idH[h] = gi;
            }
            if (lane == 0) {
                rM4[wid][0] = make_float4(s2, smH[0], smH[1], smH[2]);
                rM4[wid][1] = make_float4(__int_as_float(idH[0]), __int_as_float(idH[1]),
                                          __int_as_float(idH[2]), 0.0f);
            }
            __syncthreads();   // B2
            float4 m0 = rM4[0][0], m1 = rM4[1][0], m2 = rM4[2][0], m3 = rM4[3][0];
            float4 i0 = rM4[0][1], i1 = rM4[1][1], i2 = rM4[2][1], i3 = rM4[3][1];
            s2 = ((m0.x + m1.x) + m2.x) + m3.x;
            float var = s2 / fmaxf(n - 1.0f, 1.0f);
            float sd  = sqrtf(var);
            int col = (sd <= 0.1f) ? 0 : ((sd <= 0.3f) ? 1 : 2);
            // select col hypothesis from registers (col uniform)
            auto pickv = [&](float4 m) { return (col == 0) ? m.y : ((col == 1) ? m.z : m.w); };
            auto picki = [&](float4 i) {
                return __float_as_int((col == 0) ? i.x : ((col == 1) ? i.y : i.z));
            };
            float bv2 = pickv(m0); int bI = picki(i0);
            {
                float ov = pickv(m1); int oi = picki(i1);
                if (ov < bv2 || (ov == bv2 && oi < bI)) { bv2 = ov; bI = oi; }
                ov = pickv(m2); oi = picki(i2);
                if (ov < bv2 || (ov == bv2 && oi < bI)) { bv2 = ov; bI = oi; }
                ov = pickv(m3); oi = picki(i3);
                if (ov < bv2 || (ov == bv2 && oi < bI)) { bv2 = ov; bI = oi; }
            }
            const int chosen = bI;
            if (tid == 0) s_res[stp] = (float)chosen;

            // ---- update chosen server (owning thread; static dispatch)
            if ((chosen >> 2) == tid) {
                const int wj = chosen & 3;
                #pragma unroll
                for (int j = 0; j < 4; ++j) {
                    if (wj == j) {
                        t[j][0] = t[j][0] - w0;
                        t[j][1] = t[j][1] - w1;
                        t[j][2] = t[j][2] - w2;
                        t[j][3] = t[j][3] - w3;
                        us[j] = us[j] + 1.0f;
                        virg &= ~(1 << j);
                        #pragma unroll
                        for (int k = 0; k < 4; ++k) {
                            const float mid  = (k == 0) ? 0.4f : ((k == 1) ? 0.5f : ((k == 2) ? 0.3f : 0.5f));
                            const float high = (k == 0) ? 0.8f : ((k == 1) ? 0.8f : ((k == 2) ? 0.7f : 0.8f));
                            const float hm   = high - mid;
                            const float rmid = 1.0f / mid;
                            const float rhm  = 1.0f / hm;
                            float rem = c[j][k] - t[j][k];
                            float x = div_rn(rem, c[j][k], rc[j][k]);
                            float fv;
                            if (x <= 0.0f)      fv = 0.0f;
                            else if (x <= mid)  fv = div_rn(x, mid, rmid);
                            else if (x <= high) fv = div_rn(high - x, hm, rhm);
                            else                fv = 0.0f;
                            f[j][k] = fv;
                        }
                        fs[j] = ((f[j][0] + f[j][1]) + f[j][2]) + f[j][3];
                        float sB = ((div_rn(t[j][0], c[j][0], rc[j][0])
                                   + div_rn(t[j][1], c[j][1], rc[j][1]))
                                   + div_rn(t[j][2], c[j][2], rc[j][2]))
                                   + div_rn(t[j][3], c[j][3], rc[j][3]);
                        B[j] = 1.0f - sB * 0.25f;
                    }
                }
            }
        } else {
            if (tid == 0) s_res[stp] = -1.0f;
            __syncthreads();   // close the step: protect rA4 WAR (uniform branch)
        }
    };

    if (PACKED) {
        unsigned mcur = pm[0 * 32 + (tid >> 3)];
        float4   wcur = *(const float4*)(wlf + 0 * 4);
        const int sh = (tid & 7) * 4;
        #pragma unroll 1
        for (int stp = 0; stp < NU; ++stp) {
            const int nxt = (stp + 1 < NU) ? (stp + 1) : (NU - 1);
            unsigned mnx = pm[nxt * 32 + (tid >> 3)];
            float4   wnx = *(const float4*)(wlf + nxt * 4);
            stepf(stp, (mcur >> sh) & 0xFu, wcur);
            mcur = mnx; wcur = wnx;
        }
    } else {
        #pragma unroll 1
        for (int stp = 0; stp < NU; ++stp) {
            int u = order_g[stp];
            unsigned vm = 0;
            if (byteMode) {
                uchar4 mv = *(const uchar4*)(mbytes + (size_t)u * NS + sbase);
                vm = (mv.x ? 1u : 0u) | (mv.y ? 2u : 0u) | (mv.z ? 4u : 0u) | (mv.w ? 8u : 0u);
            } else {
                int4 mv = *(const int4*)(mwords + (size_t)u * NS + sbase);
                vm = (mv.x ? 1u : 0u) | (mv.y ? 2u : 0u) | (mv.z ? 4u : 0u) | (mv.w ? 8u : 0u);
            }
            float2 a2 = *(const float2*)(users + u * 6 + 2);
            float2 b2 = *(const float2*)(users + u * 6 + 4);
            stepf(stp, vm, make_float4(a2.x, a2.y, b2.x, b2.y));
        }
    }

    // ---- epilogue (block 0 only)
    __syncthreads();
    if (blockIdx.x != 0) return;
    float ac = 0.0f;
    for (int i = tid; i < NU; i += 256) {
        float v = s_res[i];
        out[order_g[i]] = v;
        ac += (v != -1.0f) ? 1.0f : 0.0f;
    }
    float uc = 0.0f;
    #pragma unroll
    for (int j = 0; j < 4; ++j) {
        out[NU + sbase + j] = us[j];
        uc += (us[j] != 0.0f) ? 1.0f : 0.0f;
    }
    ac = wsum(ac);
    uc = wsum(uc);
    if (lane == 0) rA4[wid][0] = make_float4(ac, uc, 0.0f, 0.0f);
    __syncthreads();
    if (tid == 0) {
        float at = ((rA4[0][0].x + rA4[1][0].x) + rA4[2][0].x) + rA4[3][0].x;
        float ut = ((rA4[0][0].y + rA4[1][0].y) + rA4[2][0].y) + rA4[3][0].y;
        out[NU + NS]     = at / 8192.0f;
        out[NU + NS + 1] = ut / 1024.0f;
    }
}

// ---------------------------------------------------------------------------
extern "C" void kernel_launch(void* const* d_in, const int* in_sizes, int n_in,
                              void* d_out, int out_size, void* d_ws, size_t ws_size,
                              hipStream_t stream) {
    const float* servers = (const float*)d_in[0];
    const float* users   = (const float*)d_in[1];
    const void*  masks   = d_in[2];
    int*   wsi = (int*)d_ws;
    float* out = (float*)d_out;

    detect_kernel<<<1, 256, 0, stream>>>((const unsigned*)masks, wsi);
    rank_kernel<<<32, 256, 0, stream>>>(users, wsi + WS_ORDER);
    if (ws_size >= WS_NEED_BYTES) {
        gather_kernel<<<NU / 256, 256, 0, stream>>>(users, wsi + WS_ORDER, (float*)(wsi + WS_WL));
        pack_kernel<<<NU * 32 / 256, 256, 0, stream>>>(masks, wsi, wsi + WS_ORDER,
                                                       (unsigned*)(wsi + WS_PM));
        alloc_kernel<true><<<256, 256, 0, stream>>>(servers, users, masks, wsi, out);
    } else {
        alloc_kernel<false><<<256, 256, 0, stream>>>(servers, users, masks, wsi, out);
    }
}